// Round 7
// baseline (442.588 us; speedup 1.0000x reference)
//
#include <hip/hip_runtime.h>
#include <hip/hip_bf16.h>
#include <stdint.h>

// Problem constants (B=2, S=2048, D=1024, H=16, hd=64)
#define DIMD 1024
#define SEQ  2048
#define NH   16
#define MROWS 4096   // B*S
#define NQ   65536   // total q rows across (b,h)

typedef __bf16 bf16_t;
typedef bf16_t bf16x8 __attribute__((ext_vector_type(8)));
typedef float  f32x4  __attribute__((ext_vector_type(4)));
typedef unsigned short u16;
typedef unsigned short u16x4 __attribute__((ext_vector_type(4)));
typedef unsigned short u16x8 __attribute__((ext_vector_type(8)));
typedef unsigned int   u32;
typedef u32 u32x2 __attribute__((ext_vector_type(2)));

static __device__ __forceinline__ f32x4 mfma16(bf16x8 a, bf16x8 b, f32x4 c) {
    return __builtin_amdgcn_mfma_f32_16x16x32_bf16(a, b, c, 0, 0, 0);
}

static __device__ __forceinline__ float fast_exp2(float x) {
#if __has_builtin(__builtin_amdgcn_exp2f)
    return __builtin_amdgcn_exp2f(x);
#else
    return exp2f(x);
#endif
}

// async global->LDS 16B per lane; lds dest must be wave-uniform base + lane*16
#define GLD16(gsrc, ldst) __builtin_amdgcn_global_load_lds(                    \
    (const __attribute__((address_space(1))) unsigned int*)(gsrc),             \
    (__attribute__((address_space(3))) unsigned int*)(ldst), 16, 0, 0)

// Split fp32 into hi/lo bf16 by truncation: x ~= hi + lo, rel err <= 2^-16
static __device__ __forceinline__ void split_bf16(float x, u16& h, u16& l) {
    u32 u = __float_as_uint(x);
    u16 hu = (u16)(u >> 16);
    float xh = __uint_as_float((u32)hu << 16);
    float lo = x - xh;
    h = hu;
    l = (u16)(__float_as_uint(lo) >> 16);
}

static __device__ __forceinline__ u32 pack_bf16(float a, float b) {
    return (__float_as_uint(a) >> 16) | (__float_as_uint(b) & 0xffff0000u);
}
static __device__ __forceinline__ u32 pack_bf16_rn(float a, float b) {
    u32 ua = __float_as_uint(a) + 0x8000u;
    u32 ub = __float_as_uint(b) + 0x8000u;
    return (ua >> 16) | (ub & 0xffff0000u);
}
static __device__ __forceinline__ float bf_to_f(u16 v) {
    return __uint_as_float((u32)v << 16);
}

// ---------------------------------------------------------------------------
// Kernel 1: W[1024][1024] f32 -> W^T split hi/lo bf16, chunk-major tile layout
// for global_load_lds: region(nt,kt)=(nt*32+kt)*4096; within: cc*1024+r*8+e.
// Grid (kt 32, nt 8, z 3), 256 thr.
// ---------------------------------------------------------------------------
__global__ __launch_bounds__(256) void transWs3(
    const float* __restrict__ w0, const float* __restrict__ w1, const float* __restrict__ w2,
    u16* __restrict__ WTsH, u16* __restrict__ WTsL) {
    const int z = blockIdx.z;
    const float* W = z == 0 ? w0 : z == 1 ? w1 : w2;
    __shared__ u16 Hs[4096], Ls[4096];
    const int tid = threadIdx.x;
    const int kt = blockIdx.x, nt = blockIdx.y;
    const int n0 = nt * 128, k0 = kt * 32;
    #pragma unroll
    for (int i = 0; i < 4; i++) {
        int f = i * 256 + tid;
        int kr = f >> 5, nc4 = (f & 31) * 4;
        f32x4 w = *(const f32x4*)&W[(size_t)(k0 + kr) * DIMD + n0 + nc4];
        int cc = kr >> 3, e = kr & 7;
        #pragma unroll
        for (int j = 0; j < 4; j++) {
            u16 hh, ll; split_bf16(w[j], hh, ll);
            Hs[cc * 1024 + (nc4 + j) * 8 + e] = hh;
            Ls[cc * 1024 + (nc4 + j) * 8 + e] = ll;
        }
    }
    __syncthreads();
    const size_t base = (size_t)z * (DIMD * DIMD) + (size_t)(nt * 32 + kt) * 4096;
    #pragma unroll
    for (int i = 0; i < 2; i++) {
        int idx = (i * 256 + tid) * 8;
        *(u16x8*)(WTsH + base + idx) = *(const u16x8*)&Hs[idx];
        *(u16x8*)(WTsL + base + idx) = *(const u16x8*)&Ls[idx];
    }
}

// ---------------------------------------------------------------------------
// Kernel 2: pre-split X (q,k,v inputs) into hi/lo bf16 chunk-major tiles,
// same region layout as WTs: region(mt,kt)=(mt*32+kt)*4096, within cc*1024+r*8+e
// (r = m%128, cc = (k%32)/8, e = k%8). xv: hi only.
// Grid (kt 32, mt 32, z 3), 256 thr.
// ---------------------------------------------------------------------------
__global__ __launch_bounds__(256) void splitX(
    const float* __restrict__ xq, const float* __restrict__ xk, const float* __restrict__ xv,
    u16* __restrict__ XqH, u16* __restrict__ XqL,
    u16* __restrict__ XkH, u16* __restrict__ XkL,
    u16* __restrict__ XvH) {
    const int z = blockIdx.z;
    const float* X = z == 0 ? xq : z == 1 ? xk : xv;
    u16* outH = z == 0 ? XqH : z == 1 ? XkH : XvH;
    u16* outL = z == 0 ? XqL : XkL;          // unused when z==2 (guarded)
    __shared__ u16 Hs[4096], Ls[4096];
    const int tid = threadIdx.x;
    const int kt = blockIdx.x, mt = blockIdx.y;
    #pragma unroll
    for (int i = 0; i < 4; i++) {
        int f = i * 256 + tid;
        int r = f >> 3, c4 = (f & 7) * 4;
        f32x4 a = *(const f32x4*)&X[(size_t)(mt * 128 + r) * DIMD + kt * 32 + c4];
        int cc = c4 >> 3, e = c4 & 7;
        #pragma unroll
        for (int j = 0; j < 4; j++) {
            u16 hh, ll; split_bf16(a[j], hh, ll);
            Hs[cc * 1024 + r * 8 + e + j] = hh;
            Ls[cc * 1024 + r * 8 + e + j] = ll;
        }
    }
    __syncthreads();
    const size_t base = (size_t)(mt * 32 + kt) * 4096;
    #pragma unroll
    for (int i = 0; i < 2; i++) {
        int idx = (i * 256 + tid) * 8;
        *(u16x8*)(outH + base + idx) = *(const u16x8*)&Hs[idx];
        if (z != 2)
            *(u16x8*)(outL + base + idx) = *(const u16x8*)&Ls[idx];
    }
}

// ---------------------------------------------------------------------------
// Kernel 3: 3 projection GEMMs (z = q/k/v). P = X @ W, split-bf16.
// Both A and B staged via global_load_lds (async, 16B) from pre-split
// chunk-major arrays -> zero staging VALU in the K-loop (m97 structure).
// z<2: 3-MFMA split (AhBh+AhBl+AlBh); z==2: 2-MFMA (AhBh+AhBl, V output is
// stored bf16-hi so the Al term is below storage error).
// Grid (x = m-tile 32, y = n-tile 8, z = 3): A-tile sharers land on one XCD.
// ---------------------------------------------------------------------------
__global__ __launch_bounds__(256, 3) void proj7(
    const u16* __restrict__ XqH, const u16* __restrict__ XqL,
    const u16* __restrict__ XkH, const u16* __restrict__ XkL,
    const u16* __restrict__ XvH,
    const u16* __restrict__ WTsH, const u16* __restrict__ WTsL,
    u16* __restrict__ qh, u16* __restrict__ ql,
    u16* __restrict__ kh, u16* __restrict__ kl,
    u16* __restrict__ vh) {

    const int z = blockIdx.z;
    const u16* AH = z == 0 ? XqH : z == 1 ? XkH : XvH;
    const u16* AL = z == 0 ? XqL : XkL;         // unused when z==2 (guarded)
    const u16* BH = WTsH + (size_t)z * (DIMD * DIMD);
    const u16* BL = WTsL + (size_t)z * (DIMD * DIMD);
    u16* outH = z == 0 ? qh : z == 1 ? kh : vh;
    u16* outL = z == 0 ? ql : kl;               // unused when z==2 (guarded)
    const float oscale = z == 0 ? 0.0450842200278f : 1.0f;  // (1/32)*log2(e)

    __shared__ u16 lds[16384];                  // AsH | AsL | BsH | BsL
    u16* AsH = lds;
    u16* AsL = lds + 4096;
    u16* BsH = lds + 8192;
    u16* BsL = lds + 12288;

    const int tid  = threadIdx.x;
    const int lane = tid & 63, wave = tid >> 6;
    const int quad = lane >> 4, l16 = lane & 15;
    const int wy = wave >> 1, wx = wave & 1;
    const int m0 = blockIdx.x * 128;            // row tile (A)
    const int n0 = blockIdx.y * 128;            // col tile (B)
    const size_t Aregion0 = (size_t)(blockIdx.x * 32) * 4096;
    const size_t Bregion0 = (size_t)(blockIdx.y * 32) * 4096;

    f32x4 acc[4][4];
    #pragma unroll
    for (int mt = 0; mt < 4; mt++)
        #pragma unroll
        for (int nt = 0; nt < 4; nt++) acc[mt][nt] = (f32x4)0.0f;

    const int c0 = tid * 8, c1 = (256 + tid) * 8;

    for (int kt = 0; kt < 32; kt++) {
        const size_t rbA = Aregion0 + (size_t)kt * 4096;
        const size_t rbB = Bregion0 + (size_t)kt * 4096;
        GLD16(AH + rbA + c0, &AsH[c0]);
        GLD16(AH + rbA + c1, &AsH[c1]);
        if (z != 2) {
            GLD16(AL + rbA + c0, &AsL[c0]);
            GLD16(AL + rbA + c1, &AsL[c1]);
        }
        GLD16(BH + rbB + c0, &BsH[c0]);
        GLD16(BH + rbB + c1, &BsH[c1]);
        GLD16(BL + rbB + c0, &BsL[c0]);
        GLD16(BL + rbB + c1, &BsL[c1]);
        __syncthreads();   // drains vmcnt (async copies)

        bf16x8 aH[4], aL[4], bH[4], bL[4];
        #pragma unroll
        for (int mt = 0; mt < 4; mt++) {
            int r = wy * 64 + mt * 16 + l16;
            aH[mt] = *(const bf16x8*)&AsH[(quad * 128 + r) * 8];
            if (z != 2) aL[mt] = *(const bf16x8*)&AsL[(quad * 128 + r) * 8];
        }
        #pragma unroll
        for (int nt = 0; nt < 4; nt++) {
            int r = wx * 64 + nt * 16 + l16;
            bH[nt] = *(const bf16x8*)&BsH[(quad * 128 + r) * 8];
            bL[nt] = *(const bf16x8*)&BsL[(quad * 128 + r) * 8];
        }
        if (z != 2) {
            #pragma unroll
            for (int mt = 0; mt < 4; mt++)
                #pragma unroll
                for (int nt = 0; nt < 4; nt++) {
                    acc[mt][nt] = mfma16(aH[mt], bH[nt], acc[mt][nt]);
                    acc[mt][nt] = mfma16(aH[mt], bL[nt], acc[mt][nt]);
                    acc[mt][nt] = mfma16(aL[mt], bH[nt], acc[mt][nt]);
                }
        } else {
            #pragma unroll
            for (int mt = 0; mt < 4; mt++)
                #pragma unroll
                for (int nt = 0; nt < 4; nt++) {
                    acc[mt][nt] = mfma16(aH[mt], bH[nt], acc[mt][nt]);
                    acc[mt][nt] = mfma16(aH[mt], bL[nt], acc[mt][nt]);
                }
        }
        __syncthreads();
    }

    #pragma unroll
    for (int mt = 0; mt < 4; mt++)
        #pragma unroll
        for (int nt = 0; nt < 4; nt++)
            #pragma unroll
            for (int r = 0; r < 4; r++) {
                int row = m0 + wy * 64 + mt * 16 + quad * 4 + r;
                int col = n0 + wx * 64 + nt * 16 + l16;
                u16 hh, ll; split_bf16(acc[mt][nt][r] * oscale, hh, ll);
                outH[(size_t)row * DIMD + col] = hh;
                if (z != 2) outL[(size_t)row * DIMD + col] = ll;
            }
}

// ---------------------------------------------------------------------------
// Kernel 4: per-head V transpose. vh is the flat projection [4096][1024];
// head slab bh = contiguous 128 rows reinterpreted as [2048 sq][64 d]
// (direct-reshape semantics). Output vt[bh][64 d][2048 sq].
// ---------------------------------------------------------------------------
__global__ __launch_bounds__(256) void transposeV(
    const u16* __restrict__ vh, u16* __restrict__ vt) {
    __shared__ u16 Ls[64][72];
    const int tid = threadIdx.x;
    const int bh = blockIdx.y;
    const int s0 = blockIdx.x * 64;
    const size_t slab = (size_t)bh * (SEQ * 64);
    #pragma unroll
    for (int i = 0; i < 2; i++) {
        int f = i * 256 + tid;
        int r = f >> 3, c = (f & 7) * 8;
        *(u16x8*)&Ls[r][c] = *(const u16x8*)(vh + slab + (size_t)(s0 + r) * 64 + c);
    }
    __syncthreads();
    #pragma unroll
    for (int i = 0; i < 2; i++) {
        int f = i * 256 + tid;
        int d = f >> 3, j = (f & 7) * 8;
        u16x8 o;
        #pragma unroll
        for (int jj = 0; jj < 8; jj++) o[jj] = Ls[j + jj][d];
        *(u16x8*)(vt + slab + (size_t)d * SEQ + s0 + j) = o;
    }
}

// ---------------------------------------------------------------------------
// Kernel 5: flash attention, S^T form, mq=4 (64 q/wave, Q-tile 256),
// KV-split 2, 64-kv staged tiles processed in two 32-kv sub-steps
// (keeps St live-range at 32 VGPRs). Single-buffered K/V LDS with register
// prefetch; per-lane scalar softmax state; P round-trip via wave-local LDS.
// Grid (bh 32, qtile 8, z 2) = 512 blocks; LDS 48KB; VGPR ~240 (256,2).
// ---------------------------------------------------------------------------
__global__ __launch_bounds__(256, 2) void flash7(
    const u16* __restrict__ qh, const u16* __restrict__ ql,
    const u16* __restrict__ kh, const u16* __restrict__ kl,
    const u16* __restrict__ vt,
    u16* __restrict__ Opart, float* __restrict__ Mpart, float* __restrict__ Lpart) {

    __shared__ u16 KH[64][72], KL[64][72], VTs[64][72];
    __shared__ u16 Ps[4][64][40];   // per-wave P: [64 q][32 kv], stride 40

    const int tid  = threadIdx.x;
    const int lane = tid & 63, wv = tid >> 6;
    const int quad = lane >> 4, l16 = lane & 15;
    const int bh = blockIdx.x, z = blockIdx.z;
    const size_t slab = (size_t)bh * (SEQ * 64);
    const int q0 = blockIdx.y * 256 + wv * 64;
    const int jbase = z * 1024;

    bf16x8 qfH[4][2], qfL[4][2];
    #pragma unroll
    for (int mq = 0; mq < 4; mq++) {
        const size_t rb = slab + (size_t)(q0 + mq * 16 + l16) * 64;
        #pragma unroll
        for (int kk = 0; kk < 2; kk++) {
            qfH[mq][kk] = *(const bf16x8*)(qh + rb + kk * 32 + quad * 8);
            qfL[mq][kk] = *(const bf16x8*)(ql + rb + kk * 32 + quad * 8);
        }
    }

    f32x4 O[4][4];
    float M[4], L[4];
    #pragma unroll
    for (int mq = 0; mq < 4; mq++) { M[mq] = -3.0e38f; L[mq] = 0.0f; }
    #pragma unroll
    for (int mq = 0; mq < 4; mq++)
        #pragma unroll
        for (int nv = 0; nv < 4; nv++) O[mq][nv] = (f32x4)0.0f;

    const int r0 = tid >> 3, c0 = (tid & 7) * 8;
    const int r1 = (256 + tid) >> 3, c1 = ((256 + tid) & 7) * 8;
    u16x8 s0, s1, s2, s3, s4, s5;

    {   // preload tile 0
        const int j0 = jbase;
        s0 = *(const u16x8*)(kh + slab + (size_t)(j0 + r0) * 64 + c0);
        s1 = *(const u16x8*)(kh + slab + (size_t)(j0 + r1) * 64 + c1);
        s2 = *(const u16x8*)(kl + slab + (size_t)(j0 + r0) * 64 + c0);
        s3 = *(const u16x8*)(kl + slab + (size_t)(j0 + r1) * 64 + c1);
        s4 = *(const u16x8*)(vt + slab + (size_t)r0 * SEQ + j0 + c0);
        s5 = *(const u16x8*)(vt + slab + (size_t)r1 * SEQ + j0 + c1);
    }
    *(u16x8*)&KH[r0][c0] = s0;  *(u16x8*)&KH[r1][c1] = s1;
    *(u16x8*)&KL[r0][c0] = s2;  *(u16x8*)&KL[r1][c1] = s3;
    *(u16x8*)&VTs[r0][c0] = s4; *(u16x8*)&VTs[r1][c1] = s5;
    __syncthreads();

    for (int t = 0; t < 16; t++) {
        if (t < 15) {   // prefetch next tile into registers
            const int j0 = jbase + (t + 1) * 64;
            s0 = *(const u16x8*)(kh + slab + (size_t)(j0 + r0) * 64 + c0);
            s1 = *(const u16x8*)(kh + slab + (size_t)(j0 + r1) * 64 + c1);
            s2 = *(const u16x8*)(kl + slab + (size_t)(j0 + r0) * 64 + c0);
            s3 = *(const u16x8*)(kl + slab + (size_t)(j0 + r1) * 64 + c1);
            s4 = *(const u16x8*)(vt + slab + (size_t)r0 * SEQ + j0 + c0);
            s5 = *(const u16x8*)(vt + slab + (size_t)r1 * SEQ + j0 + c1);
        }

        #pragma unroll
        for (int sub = 0; sub < 2; sub++) {
            // S^T = K·Q^T for this 32-kv half (split: Kh·Qh + Kl·Qh + Kh·Ql)
            f32x4 St[4][2];
            #pragma unroll
            for (int mq = 0; mq < 4; mq++)
                #pragma unroll
                for (int nt = 0; nt < 2; nt++) St[mq][nt] = (f32x4)0.0f;
            #pragma unroll
            for (int nt = 0; nt < 2; nt++) {
                const int rB = sub * 32 + nt * 16 + l16;
                #pragma unroll
                for (int kk = 0; kk < 2; kk++) {
                    bf16x8 kHf = *(const bf16x8*)&KH[rB][kk * 32 + quad * 8];
                    bf16x8 kLf = *(const bf16x8*)&KL[rB][kk * 32 + quad * 8];
                    #pragma unroll
                    for (int mq = 0; mq < 4; mq++) {
                        St[mq][nt] = mfma16(kHf, qfH[mq][kk], St[mq][nt]);
                        St[mq][nt] = mfma16(kLf, qfH[mq][kk], St[mq][nt]);
                        St[mq][nt] = mfma16(kHf, qfL[mq][kk], St[mq][nt]);
                    }
                }
            }

            // online softmax (per-lane scalar state; 2 shuffles/reduction)
            #pragma unroll
            for (int mq = 0; mq < 4; mq++) {
                float mx = St[mq][0][0];
                #pragma unroll
                for (int nt = 0; nt < 2; nt++)
                    #pragma unroll
                    for (int r = 0; r < 4; r++) mx = fmaxf(mx, St[mq][nt][r]);
                mx = fmaxf(mx, __shfl_xor(mx, 16));
                mx = fmaxf(mx, __shfl_xor(mx, 32));
                float Mn = M[mq];
                if (__any(mx > Mn)) {
                    Mn = fmaxf(Mn, mx);
                    float al = fast_exp2(M[mq] - Mn);
                    M[mq] = Mn;
                    L[mq] *= al;
                    #pragma unroll
                    for (int nv = 0; nv < 4; nv++) O[mq][nv] *= al;
                }
                float rs = 0.0f;
                #pragma unroll
                for (int nt = 0; nt < 2; nt++)
                    #pragma unroll
                    for (int r = 0; r < 4; r++) {
                        float p = fast_exp2(St[mq][nt][r] - Mn);
                        St[mq][nt][r] = p;
                        rs += p;
                    }
                rs += __shfl_xor(rs, 16);
                rs += __shfl_xor(rs, 32);
                L[mq] += rs;
                #pragma unroll
                for (int nt = 0; nt < 2; nt++) {
                    u32x2 d;
                    d[0] = pack_bf16(St[mq][nt][0], St[mq][nt][1]);
                    d[1] = pack_bf16(St[mq][nt][2], St[mq][nt][3]);
                    *(u32x2*)&Ps[wv][mq * 16 + l16][nt * 16 + quad * 4] = d;
                }
            }

            // O^T += V^T · P^T for this 32-kv half (wave-local P)
            bf16x8 pB[4];
            #pragma unroll
            for (int mq = 0; mq < 4; mq++)
                pB[mq] = *(const bf16x8*)&Ps[wv][mq * 16 + l16][quad * 8];
            #pragma unroll
            for (int nv = 0; nv < 4; nv++) {
                bf16x8 vF = *(const bf16x8*)&VTs[nv * 16 + l16][sub * 32 + quad * 8];
                #pragma unroll
                for (int mq = 0; mq < 4; mq++)
                    O[mq][nv] = mfma16(vF, pB[mq], O[mq][nv]);
            }
        }

        __syncthreads();                 // all waves done reading tile t
        if (t < 15) {
            *(u16x8*)&KH[r0][c0] = s0;  *(u16x8*)&KH[r1][c1] = s1;
            *(u16x8*)&KL[r0][c0] = s2;  *(u16x8*)&KL[r1][c1] = s3;
            *(u16x8*)&VTs[r0][c0] = s4; *(u16x8*)&VTs[r1][c1] = s5;
        }
        __syncthreads();                 // tile t+1 visible
    }

    // epilogue: bf16 unnormalized O + M, L for this half
    const int qgb = bh * SEQ + q0;
    #pragma unroll
    for (int mq = 0; mq < 4; mq++) {
        const int qg = qgb + mq * 16 + l16;
        #pragma unroll
        for (int nv = 0; nv < 4; nv++) {
            u32x2 d;
            d[0] = pack_bf16_rn(O[mq][nv][0], O[mq][nv][1]);
            d[1] = pack_bf16_rn(O[mq][nv][2], O[mq][nv][3]);
            *(u32x2*)(Opart + ((size_t)(z * NQ + qg)) * 64 + nv * 16 + quad * 4) = d;
        }
        if (quad == 0) {
            Mpart[z * NQ + qg] = M[mq];
            Lpart[z * NQ + qg] = L[mq];
        }
    }
}

// ---------------------------------------------------------------------------
// Kernel 6: combine the 2 KV-split halves -> final out [B,S,D]
// ---------------------------------------------------------------------------
__global__ __launch_bounds__(256) void combineK(
    const u16* __restrict__ Opart, const float* __restrict__ Mpart,
    const float* __restrict__ Lpart, float* __restrict__ out) {
    int idx = blockIdx.x * 256 + threadIdx.x;       // NQ*16 threads
    int qg = idx >> 4, c4 = (idx & 15) * 4;
    float M0 = Mpart[qg], M1 = Mpart[NQ + qg];
    float L0 = Lpart[qg], L1 = Lpart[NQ + qg];
    float Ms = fmaxf(M0, M1);
    float w0 = fast_exp2(M0 - Ms), w1 = fast_exp2(M1 - Ms);
    float inv = 1.0f / (w0 * L0 + w1 * L1);
    u16x4 a = *(const u16x4*)&Opart[(size_t)qg * 64 + c4];
    u16x4 b = *(const u16x4*)&Opart[((size_t)NQ + qg) * 64 + c4];
    f32x4 o;
    #pragma unroll
    for (int j = 0; j < 4; j++)
        o[j] = (w0 * bf_to_f(a[j]) + w1 * bf_to_f(b[j])) * inv;
    int bh = qg >> 11, s = qg & 2047;
    int bb = bh >> 4, h = bh & 15;
    *(f32x4*)&out[((size_t)(bb * SEQ + s)) * DIMD + h * 64 + c4] = o;
}

// ---------------------------------------------------------------------------
extern "C" void kernel_launch(void* const* d_in, const int* in_sizes, int n_in,
                              void* d_out, int out_size, void* d_ws, size_t ws_size,
                              hipStream_t stream) {
    const float* q  = (const float*)d_in[0];
    const float* k  = (const float*)d_in[1];
    const float* v  = (const float*)d_in[2];
    const float* wq = (const float*)d_in[3];
    const float* wk = (const float*)d_in[4];
    const float* wv = (const float*)d_in[5];
    float* out = (float*)d_out;

    char* ws = (char*)d_ws;
    const size_t MB = 1 << 20;
    u16* qh   = (u16*)(ws + 0 * MB);        // 8MB
    u16* ql   = (u16*)(ws + 8 * MB);        // 8MB
    u16* kh   = (u16*)(ws + 16 * MB);       // 8MB
    u16* kl   = (u16*)(ws + 24 * MB);       // 8MB
    u16* vh   = (u16*)(ws + 32 * MB);       // 8MB
    u16* vt   = (u16*)(ws + 40 * MB);       // 8MB
    u16* XqH  = (u16*)(ws + 48 * MB);       // 8MB (dead after proj7)
    u16* XqL  = (u16*)(ws + 56 * MB);       // 8MB (dead after proj7)
    u16* XkH  = (u16*)(ws + 64 * MB);       // 8MB (dead after proj7)
    u16* XkL  = (u16*)(ws + 72 * MB);       // 8MB (dead after proj7)
    u16* XvH  = (u16*)(ws + 80 * MB);       // 8MB (dead after proj7)
    u16* WTsH = (u16*)(ws + 88 * MB);       // 6MB (dead after proj7)
    u16* WTsL = (u16*)(ws + 94 * MB);       // 6MB (dead after proj7)  peak 100MB
    u16*   Opart = (u16*)(ws + 48 * MB);    // 16MB, overlays Xq*/Xk*
    float* Mpart = (float*)(ws + 88 * MB);  // 512KB, overlays WTsH
    float* Lpart = (float*)(ws + 88 * MB + 512 * 1024);

    transWs3<<<dim3(32, 8, 3), 256, 0, stream>>>(wq, wk, wv, WTsH, WTsL);

    splitX<<<dim3(32, 32, 3), 256, 0, stream>>>(q, k, v, XqH, XqL, XkH, XkL, XvH);

    proj7<<<dim3(32, 8, 3), 256, 0, stream>>>(
        XqH, XqL, XkH, XkL, XvH, WTsH, WTsL, qh, ql, kh, kl, vh);

    transposeV<<<dim3(SEQ / 64, 2 * NH), 256, 0, stream>>>(vh, vt);

    flash7<<<dim3(2 * NH, SEQ / 256, 2), 256, 0, stream>>>(
        qh, ql, kh, kl, vt, Opart, Mpart, Lpart);

    combineK<<<dim3(NQ * 16 / 256), 256, 0, stream>>>(Opart, Mpart, Lpart, out);
}